// Round 5
// baseline (288.066 us; speedup 1.0000x reference)
//
#include <hip/hip_runtime.h>
#include <hip/hip_bf16.h>

#define DIM 128
#define CHUNK 4096     // edges per block in hist/scatter
#define CAP 8192       // LDS csr segment capacity (mean bucket = 4096, 64-sigma margin)

typedef __attribute__((ext_vector_type(4))) float f32x4;
typedef __attribute__((ext_vector_type(8))) short bf16x8;

__device__ __forceinline__ float bf2f(unsigned int u16) {
    return __uint_as_float(u16 << 16);
}
__device__ __forceinline__ unsigned short f2bf(float f) {
    unsigned int u = __float_as_uint(f);
    u += 0x7fff + ((u >> 16) & 1);   // RNE
    return (unsigned short)(u >> 16);
}

// ---------------- CSR build via bucketed counting sort ----------------
// bucket b = dst >> 8 (256 nodes per bucket). pairs word = src | ((dst&255)<<17)  [needs N <= 2^17]

__global__ __launch_bounds__(256) void k_hist(const int* __restrict__ dst, int* __restrict__ bucket_cnt,
                                              int E, int nbuck) {
    __shared__ int h[512];
    int t = threadIdx.x;
    for (int i = t; i < nbuck; i += 256) h[i] = 0;
    __syncthreads();
    int base = blockIdx.x * CHUNK;
#pragma unroll
    for (int i = 0; i < 16; i++) {
        int e = base + i * 256 + t;
        if (e < E) atomicAdd(&h[dst[e] >> 8], 1);
    }
    __syncthreads();
    for (int i = t; i < nbuck; i += 256) if (h[i]) atomicAdd(&bucket_cnt[i], h[i]);
}

__global__ __launch_bounds__(512) void k_scan_buckets(const int* __restrict__ cnt, int* __restrict__ boff,
                                                      int* __restrict__ bcur, int* __restrict__ row_start,
                                                      int E, int N, int nbuck) {
    __shared__ int sp[512];
    int t = threadIdx.x;
    int v = (t < nbuck) ? cnt[t] : 0;
    sp[t] = v;
    __syncthreads();
    for (int o = 1; o < 512; o <<= 1) {
        int a = (t >= o) ? sp[t - o] : 0;
        __syncthreads();
        sp[t] += a;
        __syncthreads();
    }
    if (t < nbuck) { int ex = sp[t] - v; boff[t] = ex; bcur[t] = ex; }
    if (t == 0) { boff[nbuck] = E; row_start[N] = E; }
}

__global__ __launch_bounds__(256) void k_bucket_scatter(const int* __restrict__ src, const int* __restrict__ dst,
                                                        int* __restrict__ bcur, unsigned int* __restrict__ pairs,
                                                        int E, int nbuck) {
    __shared__ int h[512];
    __shared__ int base[512];
    int t = threadIdx.x;
    for (int i = t; i < nbuck; i += 256) h[i] = 0;
    __syncthreads();
    int cbase = blockIdx.x * CHUNK;
    int ds[16], ss[16];
#pragma unroll
    for (int i = 0; i < 16; i++) {
        int e = cbase + i * 256 + t;
        ds[i] = (e < E) ? dst[e] : -1;
        ss[i] = (e < E) ? src[e] : 0;
        if (ds[i] >= 0) atomicAdd(&h[ds[i] >> 8], 1);
    }
    __syncthreads();
    for (int i = t; i < nbuck; i += 256) {
        int c = h[i];
        if (c) base[i] = atomicAdd(&bcur[i], c);
        h[i] = 0;
    }
    __syncthreads();
#pragma unroll
    for (int i = 0; i < 16; i++) {
        if (ds[i] >= 0) {
            int b = ds[i] >> 8;
            int r = atomicAdd(&h[b], 1);
            pairs[base[b] + r] = (unsigned)ss[i] | ((unsigned)(ds[i] & 255) << 17);
        }
    }
}

// one block per bucket: build csr segment in LDS, emit row_start from in-LDS degree scan
__global__ __launch_bounds__(256) void k_bucket_build(const unsigned int* __restrict__ pairs,
                                                      const int* __restrict__ boff,
                                                      int* __restrict__ row_start, int* __restrict__ csr, int N) {
    __shared__ int deg[256];
    __shared__ int sc[256];
    __shared__ int cur[256];
    __shared__ int lcsr[CAP];
    int b = blockIdx.x, t = threadIdx.x;
    int seg = boff[b];
    int cnt = boff[b + 1] - seg;
    if (cnt > CAP) cnt = CAP;   // unreachable for uniform-random input
    deg[t] = 0;
    __syncthreads();
    for (int i = t; i < cnt; i += 256) atomicAdd(&deg[pairs[seg + i] >> 17], 1);
    __syncthreads();
    int d = deg[t];
    sc[t] = d;
    __syncthreads();
    for (int o = 1; o < 256; o <<= 1) {
        int a = (t >= o) ? sc[t - o] : 0;
        __syncthreads();
        sc[t] += a;
        __syncthreads();
    }
    int ex = sc[t] - d;
    int node = (b << 8) + t;
    if (node < N) row_start[node] = seg + ex;
    cur[t] = ex;
    __syncthreads();
    for (int i = t; i < cnt; i += 256) {
        unsigned pk = pairs[seg + i];
        int p = atomicAdd(&cur[pk >> 17], 1);
        lcsr[p] = (int)(pk & 0x1FFFFu);
    }
    __syncthreads();
    for (int i = t; i < cnt; i += 256) csr[seg + i] = lcsr[i];
}

// ---------------- f32 -> bf16 cast (8 elems/thread) ----------------

__global__ __launch_bounds__(256) void k_cast_bf16(const float* __restrict__ in, unsigned short* __restrict__ out, int n8) {
    int i = blockIdx.x * 256 + threadIdx.x;
    if (i >= n8) return;
    const float4* ip = (const float4*)in;
    float4 a = ip[2 * i], b = ip[2 * i + 1];
    unsigned short o[8] = { f2bf(a.x), f2bf(a.y), f2bf(a.z), f2bf(a.w),
                            f2bf(b.x), f2bf(b.y), f2bf(b.z), f2bf(b.w) };
    ((uint4*)out)[i] = *(uint4*)o;
}

// ---------------- weight pack: Wcat[256][128] -> MFMA B-fragment order, bf16 ----------------

__global__ __launch_bounds__(256) void k_packW(const float* __restrict__ Wl, const float* __restrict__ Wr,
                                               unsigned short* __restrict__ Wp) {
    int t = blockIdx.x * 256 + threadIdx.x;   // 4096 threads total
    int lane = t & 63;
    int frag = t >> 6;                        // 0..63
    int nt = frag >> 3, ks = frag & 7;
    int col = nt * 16 + (lane & 15);
    int kbase = ks * 32 + (lane >> 4) * 8;
    unsigned short o[8];
#pragma unroll
    for (int e = 0; e < 8; e++) {
        int k = kbase + e;
        float w = (k < DIM) ? Wl[k * DIM + col] : Wr[(k - DIM) * DIM + col];
        o[e] = f2bf(w);
    }
    ((uint4*)Wp)[t] = *(uint4*)o;
}

// ---------------- fused: mean-aggregate -> dual-GEMM (MFMA) -> bias -> LN -> ReLU -> {Hb | head} ----
// Block = 256 thr = 4 waves = 64 nodes. Wave w aggregates rows w*16..w*16+15 into the swizzled LDS
// A-tile (k=0..127), all threads copy self-rows into k=128..255, then MFMA vs packed weights.
// Aggregation inner loop is the round-3-proven pattern: direct csr loads, stride-4 per sub-group.

#define ACC8(v)                                                   \
    do {                                                          \
        a[0] += bf2f((v).x & 0xffffu); a[1] += bf2f((v).x >> 16); \
        a[2] += bf2f((v).y & 0xffffu); a[3] += bf2f((v).y >> 16); \
        a[4] += bf2f((v).z & 0xffffu); a[5] += bf2f((v).z >> 16); \
        a[6] += bf2f((v).w & 0xffffu); a[7] += bf2f((v).w >> 16); \
    } while (0)

template <bool HEAD>
__global__ __launch_bounds__(256) void fused_sage(const uint4* __restrict__ feat4,        // gather src [N][16]
                                                  const unsigned short* __restrict__ Xb,  // self rows [N][128]
                                                  const int* __restrict__ row_start,
                                                  const int* __restrict__ csr,
                                                  const uint4* __restrict__ Wp,
                                                  const float* __restrict__ bias,
                                                  const float* __restrict__ lnw, const float* __restrict__ lnb,
                                                  unsigned short* __restrict__ Hb,        // if !HEAD
                                                  const float* __restrict__ fcW,
                                                  const float* __restrict__ fcb,
                                                  float* __restrict__ out,                // if HEAD
                                                  int N) {
    __shared__ uint4 As4[2048];   // 32 KB: [64 rows][256 k] bf16, XOR-swizzled
    char* As = (char*)As4;
    int t = threadIdx.x;
    int lane = t & 63;
    int wave = t >> 6;
    int m0 = blockIdx.x * 64;

    // ---- phase 1a: copy self rows into k = 128..255 (units 16..31)
#pragma unroll
    for (int i = 0; i < 4; i++) {
        int idx = i * 256 + t;                // 0..1023
        int row = idx >> 4;
        int u = 16 + (idx & 15);
        int grow = m0 + row;
        uint4 v = make_uint4(0u, 0u, 0u, 0u);
        if (grow < N) v = *(const uint4*)(Xb + (size_t)grow * DIM + (idx & 15) * 8);
        int lb = (row * 512 + u * 16) ^ ((row & 7) << 4);
        *(uint4*)(As + lb) = v;
    }

    // ---- phase 1b: mean aggregation into k = 0..127 (units 0..15), round-3 gather pattern
    int sub = lane >> 4, fo = lane & 15;
    for (int n = 0; n < 16; n++) {
        int row = wave * 16 + n;
        int gnode = m0 + row;
        float a[8] = {0.f, 0.f, 0.f, 0.f, 0.f, 0.f, 0.f, 0.f};
        int nb = 0;
        if (gnode < N) {
            int s = row_start[gnode], e = row_start[gnode + 1];
            nb = e - s;
            int base = s + sub;
            for (; base + 12 < e; base += 16) {       // 4 gathers in flight per lane
                int i0 = csr[base], i1 = csr[base + 4], i2 = csr[base + 8], i3 = csr[base + 12];
                uint4 v0 = feat4[(size_t)i0 * 16 + fo];
                uint4 v1 = feat4[(size_t)i1 * 16 + fo];
                uint4 v2 = feat4[(size_t)i2 * 16 + fo];
                uint4 v3 = feat4[(size_t)i3 * 16 + fo];
                ACC8(v0); ACC8(v1); ACC8(v2); ACC8(v3);
            }
            for (; base < e; base += 4) {
                int id = csr[base];
                uint4 v = feat4[(size_t)id * 16 + fo];
                ACC8(v);
            }
        }
#pragma unroll
        for (int q = 0; q < 8; q++) {
            a[q] += __shfl_xor(a[q], 16, 64);
            a[q] += __shfl_xor(a[q], 32, 64);
        }
        if (sub == 0) {
            float inv = 1.0f / (float)max(nb, 1);
            uint4 o;
            o.x = (unsigned)f2bf(a[0] * inv) | ((unsigned)f2bf(a[1] * inv) << 16);
            o.y = (unsigned)f2bf(a[2] * inv) | ((unsigned)f2bf(a[3] * inv) << 16);
            o.z = (unsigned)f2bf(a[4] * inv) | ((unsigned)f2bf(a[5] * inv) << 16);
            o.w = (unsigned)f2bf(a[6] * inv) | ((unsigned)f2bf(a[7] * inv) << 16);
            int lb = (row * 512 + fo * 16) ^ ((row & 7) << 4);
            *(uint4*)(As + lb) = o;
        }
    }
    __syncthreads();

    // ---- phase 2: MFMA
    f32x4 acc[8];
#pragma unroll
    for (int nt = 0; nt < 8; nt++) acc[nt] = (f32x4)(0.f);

    int arow = wave * 16 + (lane & 15);
    int kq = (lane >> 4) * 16;
#pragma unroll
    for (int ks = 0; ks < 8; ks++) {
        int lb = (arow * 512 + ks * 64 + kq) ^ ((arow & 7) << 4);
        bf16x8 afrag = *(const bf16x8*)(As + lb);
#pragma unroll
        for (int nt = 0; nt < 8; nt++) {
            uint4 bw = Wp[(nt * 8 + ks) * 64 + lane];
            bf16x8 bfrag = *(bf16x8*)&bw;
            acc[nt] = __builtin_amdgcn_mfma_f32_16x16x32_bf16(afrag, bfrag, acc[nt], 0, 0, 0);
        }
    }

    // ---- phase 3: + bias, in-register LayerNorm over 128 cols, ReLU, then store or head-dot
    int col = lane & 15;
    float bv[8], lw[8], lbv[8], fw[8];
#pragma unroll
    for (int nt = 0; nt < 8; nt++) {
        bv[nt]  = bias[nt * 16 + col];
        lw[nt]  = lnw [nt * 16 + col];
        lbv[nt] = lnb [nt * 16 + col];
        if (HEAD) fw[nt] = fcW[nt * 16 + col];
    }
#pragma unroll
    for (int nt = 0; nt < 8; nt++) {
#pragma unroll
        for (int r = 0; r < 4; r++) acc[nt][r] += bv[nt];
    }

#pragma unroll
    for (int r = 0; r < 4; r++) {
        float s = 0.f;
#pragma unroll
        for (int nt = 0; nt < 8; nt++) s += acc[nt][r];
        s += __shfl_xor(s, 1, 64); s += __shfl_xor(s, 2, 64);
        s += __shfl_xor(s, 4, 64); s += __shfl_xor(s, 8, 64);
        float mu = s * (1.0f / 128.0f);
        float q = 0.f;
#pragma unroll
        for (int nt = 0; nt < 8; nt++) { float dd = acc[nt][r] - mu; q += dd * dd; }
        q += __shfl_xor(q, 1, 64); q += __shfl_xor(q, 2, 64);
        q += __shfl_xor(q, 4, 64); q += __shfl_xor(q, 8, 64);
        float rs = rsqrtf(q * (1.0f / 128.0f) + 1e-5f);

        int grow = m0 + wave * 16 + 4 * (lane >> 4) + r;
        if (HEAD) {
            float dot = 0.f;
#pragma unroll
            for (int nt = 0; nt < 8; nt++) {
                float o = (acc[nt][r] - mu) * rs * lw[nt] + lbv[nt];
                dot += fmaxf(o, 0.0f) * fw[nt];
            }
            dot += __shfl_xor(dot, 1, 64); dot += __shfl_xor(dot, 2, 64);
            dot += __shfl_xor(dot, 4, 64); dot += __shfl_xor(dot, 8, 64);
            if (col == 0 && grow < N) out[grow] = dot + fcb[0];
        } else if (grow < N) {
            size_t rb = (size_t)grow * DIM;
#pragma unroll
            for (int nt = 0; nt < 8; nt++) {
                float o = (acc[nt][r] - mu) * rs * lw[nt] + lbv[nt];
                o = fmaxf(o, 0.0f);
                Hb[rb + nt * 16 + col] = f2bf(o);
            }
        }
    }
}

// ---------------- launch ----------------

extern "C" void kernel_launch(void* const* d_in, const int* in_sizes, int n_in,
                              void* d_out, int out_size, void* d_ws, size_t ws_size,
                              hipStream_t stream) {
    const float* x    = (const float*)d_in[0];
    const int*   edge = (const int*)d_in[1];
    const float* W1l  = (const float*)d_in[2];
    const float* W1r  = (const float*)d_in[3];
    const float* b1   = (const float*)d_in[4];
    const float* W2l  = (const float*)d_in[5];
    const float* W2r  = (const float*)d_in[6];
    const float* b2   = (const float*)d_in[7];
    const float* ln1w = (const float*)d_in[8];
    const float* ln1b = (const float*)d_in[9];
    const float* ln2w = (const float*)d_in[10];
    const float* ln2b = (const float*)d_in[11];
    const float* fcW  = (const float*)d_in[12];
    const float* fcb  = (const float*)d_in[13];

    const int N = in_sizes[0] / DIM;
    const int E = in_sizes[1] / 2;
    const int* src = edge;
    const int* dst = edge + E;
    const int nbuck = (N + 255) >> 8;

    char* ws = (char*)d_ws;
    size_t off = 0;
    auto alloc = [&](size_t bytes) -> void* {
        void* p = ws + off;
        off = (off + bytes + 255) & ~(size_t)255;
        return p;
    };
    int*            bucket_cnt = (int*)alloc((size_t)(nbuck + 1) * 4);
    int*            boff       = (int*)alloc((size_t)(nbuck + 1) * 4);
    int*            bcur       = (int*)alloc((size_t)(nbuck + 1) * 4);
    int*            row_start  = (int*)alloc((size_t)(N + 1) * 4);
    unsigned int*   pairs      = (unsigned int*)alloc((size_t)E * 4);
    int*            csr        = (int*)alloc((size_t)E * 4);
    unsigned short* xb         = (unsigned short*)alloc((size_t)N * DIM * 2);
    unsigned short* hb1        = (unsigned short*)alloc((size_t)N * DIM * 2);
    unsigned short* Wp1        = (unsigned short*)alloc((size_t)256 * DIM * 2);
    unsigned short* Wp2        = (unsigned short*)alloc((size_t)256 * DIM * 2);
    (void)ws_size; (void)n_in; (void)out_size;

    hipMemsetAsync(bucket_cnt, 0, (size_t)(nbuck + 1) * 4, stream);

    int egrid = (E + CHUNK - 1) / CHUNK;
    // CSR build (bucketed counting sort; also emits row_start)
    k_hist          <<<egrid, 256, 0, stream>>>(dst, bucket_cnt, E, nbuck);
    k_scan_buckets  <<<1, 512, 0, stream>>>(bucket_cnt, boff, bcur, row_start, E, N, nbuck);
    k_bucket_scatter<<<egrid, 256, 0, stream>>>(src, dst, bcur, pairs, E, nbuck);
    k_bucket_build  <<<nbuck, 256, 0, stream>>>(pairs, boff, row_start, csr, N);

    // weight packing + input cast
    k_packW<<<16, 256, 0, stream>>>(W1l, W1r, Wp1);
    k_packW<<<16, 256, 0, stream>>>(W2l, W2r, Wp2);
    k_cast_bf16<<<(N * DIM / 8 + 255) / 256, 256, 0, stream>>>(x, xb, N * DIM / 8);

    int mmGrid = (N + 63) / 64;
    // layer 1: aggregate + GEMM + LN + ReLU -> hb1
    fused_sage<false><<<mmGrid, 256, 0, stream>>>((const uint4*)xb, xb, row_start, csr,
                                                  (const uint4*)Wp1, b1, ln1w, ln1b,
                                                  hb1, nullptr, nullptr, nullptr, N);
    // layer 2 + head: aggregate + GEMM + LN + ReLU + dot(fcW) -> d_out
    fused_sage<true><<<mmGrid, 256, 0, stream>>>((const uint4*)hb1, hb1, row_start, csr,
                                                 (const uint4*)Wp2, b2, ln2w, ln2b,
                                                 nullptr, fcW, fcb, (float*)d_out, N);
}

// Round 6
// 242.999 us; speedup vs baseline: 1.1855x; 1.1855x over previous
//
#include <hip/hip_runtime.h>
#include <hip/hip_bf16.h>

#define DIM 128
#define CHUNK 4096     // edges per block in hist/scatter
#define CAP 8192       // LDS csr segment capacity (mean bucket = 4096, 64-sigma margin)

typedef __attribute__((ext_vector_type(4))) float f32x4;
typedef __attribute__((ext_vector_type(8))) short bf16x8;

__device__ __forceinline__ float bf2f(unsigned int u16) {
    return __uint_as_float(u16 << 16);
}
__device__ __forceinline__ unsigned short f2bf(float f) {
    unsigned int u = __float_as_uint(f);
    u += 0x7fff + ((u >> 16) & 1);   // RNE
    return (unsigned short)(u >> 16);
}

// ---------------- CSR build via bucketed counting sort ----------------
// bucket b = dst >> 8 (256 nodes per bucket). pairs word = src | ((dst&255)<<17)  [needs N <= 2^17]

__global__ __launch_bounds__(256) void k_hist(const int* __restrict__ dst, int* __restrict__ bucket_cnt,
                                              int E, int nbuck) {
    __shared__ int h[512];
    int t = threadIdx.x;
    for (int i = t; i < nbuck; i += 256) h[i] = 0;
    __syncthreads();
    int base = blockIdx.x * CHUNK;
#pragma unroll
    for (int i = 0; i < 16; i++) {
        int e = base + i * 256 + t;
        if (e < E) atomicAdd(&h[dst[e] >> 8], 1);
    }
    __syncthreads();
    for (int i = t; i < nbuck; i += 256) if (h[i]) atomicAdd(&bucket_cnt[i], h[i]);
}

__global__ __launch_bounds__(512) void k_scan_buckets(const int* __restrict__ cnt, int* __restrict__ boff,
                                                      int* __restrict__ bcur, int* __restrict__ row_start,
                                                      int E, int N, int nbuck) {
    __shared__ int sp[512];
    int t = threadIdx.x;
    int v = (t < nbuck) ? cnt[t] : 0;
    sp[t] = v;
    __syncthreads();
    for (int o = 1; o < 512; o <<= 1) {
        int a = (t >= o) ? sp[t - o] : 0;
        __syncthreads();
        sp[t] += a;
        __syncthreads();
    }
    if (t < nbuck) { int ex = sp[t] - v; boff[t] = ex; bcur[t] = ex; }
    if (t == 0) { boff[nbuck] = E; row_start[N] = E; }
}

__global__ __launch_bounds__(256) void k_bucket_scatter(const int* __restrict__ src, const int* __restrict__ dst,
                                                        int* __restrict__ bcur, unsigned int* __restrict__ pairs,
                                                        int E, int nbuck) {
    __shared__ int h[512];
    __shared__ int base[512];
    int t = threadIdx.x;
    for (int i = t; i < nbuck; i += 256) h[i] = 0;
    __syncthreads();
    int cbase = blockIdx.x * CHUNK;
    int ds[16], ss[16];
#pragma unroll
    for (int i = 0; i < 16; i++) {
        int e = cbase + i * 256 + t;
        ds[i] = (e < E) ? dst[e] : -1;
        ss[i] = (e < E) ? src[e] : 0;
        if (ds[i] >= 0) atomicAdd(&h[ds[i] >> 8], 1);
    }
    __syncthreads();
    for (int i = t; i < nbuck; i += 256) {
        int c = h[i];
        if (c) base[i] = atomicAdd(&bcur[i], c);
        h[i] = 0;
    }
    __syncthreads();
#pragma unroll
    for (int i = 0; i < 16; i++) {
        if (ds[i] >= 0) {
            int b = ds[i] >> 8;
            int r = atomicAdd(&h[b], 1);
            pairs[base[b] + r] = (unsigned)ss[i] | ((unsigned)(ds[i] & 255) << 17);
        }
    }
}

// one block per bucket: build csr segment in LDS, emit row_start from in-LDS degree scan
__global__ __launch_bounds__(256) void k_bucket_build(const unsigned int* __restrict__ pairs,
                                                      const int* __restrict__ boff,
                                                      int* __restrict__ row_start, int* __restrict__ csr, int N) {
    __shared__ int deg[256];
    __shared__ int sc[256];
    __shared__ int cur[256];
    __shared__ int lcsr[CAP];
    int b = blockIdx.x, t = threadIdx.x;
    int seg = boff[b];
    int cnt = boff[b + 1] - seg;
    if (cnt > CAP) cnt = CAP;   // unreachable for uniform-random input
    deg[t] = 0;
    __syncthreads();
    for (int i = t; i < cnt; i += 256) atomicAdd(&deg[pairs[seg + i] >> 17], 1);
    __syncthreads();
    int d = deg[t];
    sc[t] = d;
    __syncthreads();
    for (int o = 1; o < 256; o <<= 1) {
        int a = (t >= o) ? sc[t - o] : 0;
        __syncthreads();
        sc[t] += a;
        __syncthreads();
    }
    int ex = sc[t] - d;
    int node = (b << 8) + t;
    if (node < N) row_start[node] = seg + ex;
    cur[t] = ex;
    __syncthreads();
    for (int i = t; i < cnt; i += 256) {
        unsigned pk = pairs[seg + i];
        int p = atomicAdd(&cur[pk >> 17], 1);
        lcsr[p] = (int)(pk & 0x1FFFFu);
    }
    __syncthreads();
    for (int i = t; i < cnt; i += 256) csr[seg + i] = lcsr[i];
}

// ---------------- f32 -> bf16 cast (8 elems/thread) ----------------

__global__ __launch_bounds__(256) void k_cast_bf16(const float* __restrict__ in, unsigned short* __restrict__ out, int n8) {
    int i = blockIdx.x * 256 + threadIdx.x;
    if (i >= n8) return;
    const float4* ip = (const float4*)in;
    float4 a = ip[2 * i], b = ip[2 * i + 1];
    unsigned short o[8] = { f2bf(a.x), f2bf(a.y), f2bf(a.z), f2bf(a.w),
                            f2bf(b.x), f2bf(b.y), f2bf(b.z), f2bf(b.w) };
    ((uint4*)out)[i] = *(uint4*)o;
}

// ---------------- weight pack: Wcat[256][128] -> MFMA B-fragment order, bf16 ----------------

__global__ __launch_bounds__(256) void k_packW(const float* __restrict__ Wl, const float* __restrict__ Wr,
                                               unsigned short* __restrict__ Wp) {
    int t = blockIdx.x * 256 + threadIdx.x;   // 4096 threads total
    int lane = t & 63;
    int frag = t >> 6;                        // 0..63
    int nt = frag >> 3, ks = frag & 7;
    int col = nt * 16 + (lane & 15);
    int kbase = ks * 32 + (lane >> 4) * 8;
    unsigned short o[8];
#pragma unroll
    for (int e = 0; e < 8; e++) {
        int k = kbase + e;
        float w = (k < DIM) ? Wl[k * DIM + col] : Wr[(k - DIM) * DIM + col];
        o[e] = f2bf(w);
    }
    ((uint4*)Wp)[t] = *(uint4*)o;
}

// ---------------- mean aggregation, column-half split with XCD-parity mapping ----------------
// blockIdx b: half = (b>>2)&1, node-group g = (b>>3)*4 + (b&3). With round-robin block->XCD
// dispatch, XCDs 0-3 only gather cols 0-63 and XCDs 4-7 cols 64-127 -> halves each XCD's
// compulsory L2 fill. Wave handles 2 nodes (32 lanes each): sub=(lane>>3)&3, fo=lane&7.
// Gather pattern per node: 4 subs x 4-deep = 16 x 128B lines in flight (round-3-proven stream).

#define ACC8(v)                                                   \
    do {                                                          \
        a[0] += bf2f((v).x & 0xffffu); a[1] += bf2f((v).x >> 16); \
        a[2] += bf2f((v).y & 0xffffu); a[3] += bf2f((v).y >> 16); \
        a[4] += bf2f((v).z & 0xffffu); a[5] += bf2f((v).z >> 16); \
        a[6] += bf2f((v).w & 0xffffu); a[7] += bf2f((v).w >> 16); \
    } while (0)

__global__ __launch_bounds__(256) void k_aggregate_bf16(const uint4* __restrict__ feat4,   // [N][16]
                                                        const int* __restrict__ row_start,
                                                        const int* __restrict__ csr,
                                                        uint4* __restrict__ mean4, int N) {
    int b = blockIdx.x;
    int half = (b >> 2) & 1;
    int g = (b >> 3) * 4 + (b & 3);
    int t = threadIdx.x;
    int lane = t & 63;
    int node = g * 8 + (t >> 6) * 2 + (lane >> 5);
    if (node >= N) return;
    int sub = (lane >> 3) & 3;
    int fo  = lane & 7;
    int ucol = half * 8 + fo;                 // uint4 unit within row

    int s = row_start[node], e = row_start[node + 1];
    int nb = e - s;
    float a[8] = {0.f, 0.f, 0.f, 0.f, 0.f, 0.f, 0.f, 0.f};
    int base = s + sub;
    for (; base + 12 < e; base += 16) {       // 4 gathers in flight per lane
        int i0 = csr[base], i1 = csr[base + 4], i2 = csr[base + 8], i3 = csr[base + 12];
        uint4 v0 = feat4[(size_t)i0 * 16 + ucol];
        uint4 v1 = feat4[(size_t)i1 * 16 + ucol];
        uint4 v2 = feat4[(size_t)i2 * 16 + ucol];
        uint4 v3 = feat4[(size_t)i3 * 16 + ucol];
        ACC8(v0); ACC8(v1); ACC8(v2); ACC8(v3);
    }
    for (; base < e; base += 4) {
        int id = csr[base];
        uint4 v = feat4[(size_t)id * 16 + ucol];
        ACC8(v);
    }
#pragma unroll
    for (int q = 0; q < 8; q++) {             // combine the 4 subs (within 32-lane node group)
        a[q] += __shfl_xor(a[q], 8, 64);
        a[q] += __shfl_xor(a[q], 16, 64);
    }
    if (sub == 0) {
        float inv = 1.0f / (float)max(nb, 1);
        uint4 o;
        o.x = (unsigned)f2bf(a[0] * inv) | ((unsigned)f2bf(a[1] * inv) << 16);
        o.y = (unsigned)f2bf(a[2] * inv) | ((unsigned)f2bf(a[3] * inv) << 16);
        o.z = (unsigned)f2bf(a[4] * inv) | ((unsigned)f2bf(a[5] * inv) << 16);
        o.w = (unsigned)f2bf(a[6] * inv) | ((unsigned)f2bf(a[7] * inv) << 16);
        mean4[(size_t)node * 16 + ucol] = o;
    }
}

// ---------------- dual-GEMM + bias + LayerNorm + ReLU (+ optional fused head) -------------
// H = LNrelu( [A | X] @ Wp + b ); if HEAD, out = H @ fcW + fcb instead of storing H.

template <bool HEAD>
__global__ __launch_bounds__(256) void sage_mm_mfma(const unsigned short* __restrict__ Ab,  // [N][128] bf16
                                                    const unsigned short* __restrict__ Xb,  // [N][128] bf16
                                                    const uint4* __restrict__ Wp,           // packed 64 frags
                                                    const float* __restrict__ bias,
                                                    const float* __restrict__ lnw, const float* __restrict__ lnb,
                                                    unsigned short* __restrict__ Hb,        // if !HEAD
                                                    const float* __restrict__ fcW,
                                                    const float* __restrict__ fcb,
                                                    float* __restrict__ out,                // if HEAD
                                                    int N) {
    __shared__ uint4 As4[2048];   // 32 KB: [64 rows][256 k] bf16, XOR-swizzled
    char* As = (char*)As4;
    int t = threadIdx.x;
    int lane = t & 63;
    int wave = t >> 6;
    int m0 = blockIdx.x * 64;

    // stage A-tile: unit = 16B (8 bf16 of k); 2048 units, 8 per thread
#pragma unroll
    for (int i = 0; i < 8; i++) {
        int idx = i * 256 + t;
        int row = idx >> 5, u = idx & 31;     // u: 16B-unit within row (k = u*8)
        int grow = m0 + row;
        uint4 v = make_uint4(0u, 0u, 0u, 0u);
        if (grow < N) {
            const unsigned short* srcp = (u < 16) ? (Ab + (size_t)grow * DIM + u * 8)
                                                  : (Xb + (size_t)grow * DIM + (u - 16) * 8);
            v = *(const uint4*)srcp;
        }
        int lb = (row * 512 + u * 16) ^ ((row & 7) << 4);
        *(uint4*)(As + lb) = v;
    }
    __syncthreads();

    f32x4 acc[8];
#pragma unroll
    for (int nt = 0; nt < 8; nt++) acc[nt] = (f32x4)(0.f);

    int arow = wave * 16 + (lane & 15);
    int kq = (lane >> 4) * 16;
#pragma unroll
    for (int ks = 0; ks < 8; ks++) {
        int lb = (arow * 512 + ks * 64 + kq) ^ ((arow & 7) << 4);
        bf16x8 afrag = *(const bf16x8*)(As + lb);
#pragma unroll
        for (int nt = 0; nt < 8; nt++) {
            uint4 bw = Wp[(nt * 8 + ks) * 64 + lane];
            bf16x8 bfrag = *(bf16x8*)&bw;
            acc[nt] = __builtin_amdgcn_mfma_f32_16x16x32_bf16(afrag, bfrag, acc[nt], 0, 0, 0);
        }
    }

    // epilogue: + bias, in-register LayerNorm over 128 cols, ReLU, then store or head-dot
    int col = lane & 15;
    float bv[8], lw[8], lbv[8], fw[8];
#pragma unroll
    for (int nt = 0; nt < 8; nt++) {
        bv[nt]  = bias[nt * 16 + col];
        lw[nt]  = lnw [nt * 16 + col];
        lbv[nt] = lnb [nt * 16 + col];
        if (HEAD) fw[nt] = fcW[nt * 16 + col];
    }
#pragma unroll
    for (int nt = 0; nt < 8; nt++) {
#pragma unroll
        for (int r = 0; r < 4; r++) acc[nt][r] += bv[nt];
    }

#pragma unroll
    for (int r = 0; r < 4; r++) {
        float s = 0.f;
#pragma unroll
        for (int nt = 0; nt < 8; nt++) s += acc[nt][r];
        s += __shfl_xor(s, 1, 64); s += __shfl_xor(s, 2, 64);
        s += __shfl_xor(s, 4, 64); s += __shfl_xor(s, 8, 64);
        float mu = s * (1.0f / 128.0f);
        float q = 0.f;
#pragma unroll
        for (int nt = 0; nt < 8; nt++) { float dd = acc[nt][r] - mu; q += dd * dd; }
        q += __shfl_xor(q, 1, 64); q += __shfl_xor(q, 2, 64);
        q += __shfl_xor(q, 4, 64); q += __shfl_xor(q, 8, 64);
        float rs = rsqrtf(q * (1.0f / 128.0f) + 1e-5f);

        int grow = m0 + wave * 16 + 4 * (lane >> 4) + r;
        if (HEAD) {
            float dot = 0.f;
#pragma unroll
            for (int nt = 0; nt < 8; nt++) {
                float o = (acc[nt][r] - mu) * rs * lw[nt] + lbv[nt];
                dot += fmaxf(o, 0.0f) * fw[nt];
            }
            dot += __shfl_xor(dot, 1, 64); dot += __shfl_xor(dot, 2, 64);
            dot += __shfl_xor(dot, 4, 64); dot += __shfl_xor(dot, 8, 64);
            if (col == 0 && grow < N) out[grow] = dot + fcb[0];
        } else if (grow < N) {
            size_t rb = (size_t)grow * DIM;
#pragma unroll
            for (int nt = 0; nt < 8; nt++) {
                float o = (acc[nt][r] - mu) * rs * lw[nt] + lbv[nt];
                o = fmaxf(o, 0.0f);
                Hb[rb + nt * 16 + col] = f2bf(o);
            }
        }
    }
}

// ---------------- launch ----------------

extern "C" void kernel_launch(void* const* d_in, const int* in_sizes, int n_in,
                              void* d_out, int out_size, void* d_ws, size_t ws_size,
                              hipStream_t stream) {
    const float* x    = (const float*)d_in[0];
    const int*   edge = (const int*)d_in[1];
    const float* W1l  = (const float*)d_in[2];
    const float* W1r  = (const float*)d_in[3];
    const float* b1   = (const float*)d_in[4];
    const float* W2l  = (const float*)d_in[5];
    const float* W2r  = (const float*)d_in[6];
    const float* b2   = (const float*)d_in[7];
    const float* ln1w = (const float*)d_in[8];
    const float* ln1b = (const float*)d_in[9];
    const float* ln2w = (const float*)d_in[10];
    const float* ln2b = (const float*)d_in[11];
    const float* fcW  = (const float*)d_in[12];
    const float* fcb  = (const float*)d_in[13];

    const int N = in_sizes[0] / DIM;
    const int E = in_sizes[1] / 2;
    const int* src = edge;
    const int* dst = edge + E;
    const int nbuck = (N + 255) >> 8;

    char* ws = (char*)d_ws;
    size_t off = 0;
    auto alloc = [&](size_t bytes) -> void* {
        void* p = ws + off;
        off = (off + bytes + 255) & ~(size_t)255;
        return p;
    };
    int*            bucket_cnt = (int*)alloc((size_t)(nbuck + 1) * 4);
    int*            boff       = (int*)alloc((size_t)(nbuck + 1) * 4);
    int*            bcur       = (int*)alloc((size_t)(nbuck + 1) * 4);
    int*            row_start  = (int*)alloc((size_t)(N + 1) * 4);
    unsigned int*   pairs      = (unsigned int*)alloc((size_t)E * 4);
    int*            csr        = (int*)alloc((size_t)E * 4);
    unsigned short* xb         = (unsigned short*)alloc((size_t)N * DIM * 2);
    unsigned short* meanb      = (unsigned short*)alloc((size_t)N * DIM * 2);
    unsigned short* hb1        = (unsigned short*)alloc((size_t)N * DIM * 2);
    unsigned short* Wp1        = (unsigned short*)alloc((size_t)256 * DIM * 2);
    unsigned short* Wp2        = (unsigned short*)alloc((size_t)256 * DIM * 2);
    (void)ws_size; (void)n_in; (void)out_size;

    hipMemsetAsync(bucket_cnt, 0, (size_t)(nbuck + 1) * 4, stream);

    int egrid = (E + CHUNK - 1) / CHUNK;
    // CSR build (bucketed counting sort; also emits row_start)
    k_hist          <<<egrid, 256, 0, stream>>>(dst, bucket_cnt, E, nbuck);
    k_scan_buckets  <<<1, 512, 0, stream>>>(bucket_cnt, boff, bcur, row_start, E, N, nbuck);
    k_bucket_scatter<<<egrid, 256, 0, stream>>>(src, dst, bcur, pairs, E, nbuck);
    k_bucket_build  <<<nbuck, 256, 0, stream>>>(pairs, boff, row_start, csr, N);

    // weight packing + input cast
    k_packW<<<16, 256, 0, stream>>>(W1l, W1r, Wp1);
    k_packW<<<16, 256, 0, stream>>>(W2l, W2r, Wp2);
    k_cast_bf16<<<(N * DIM / 8 + 255) / 256, 256, 0, stream>>>(x, xb, N * DIM / 8);

    // aggregate grid: 8 nodes per block, 2 halves, node-group padded to multiple of 4
    int G = (N + 7) / 8;
    int Gpad = (G + 3) & ~3;
    int aggGrid = 2 * Gpad;
    int mmGrid = (N + 63) / 64;

    // layer 1
    k_aggregate_bf16<<<aggGrid, 256, 0, stream>>>((const uint4*)xb, row_start, csr,
                                                  (uint4*)meanb, N);
    sage_mm_mfma<false><<<mmGrid, 256, 0, stream>>>(meanb, xb, (const uint4*)Wp1, b1, ln1w, ln1b,
                                                    hb1, nullptr, nullptr, nullptr, N);
    // layer 2 (+ fused head)
    k_aggregate_bf16<<<aggGrid, 256, 0, stream>>>((const uint4*)hb1, row_start, csr,
                                                  (uint4*)meanb, N);
    sage_mm_mfma<true><<<mmGrid, 256, 0, stream>>>(meanb, hb1, (const uint4*)Wp2, b2, ln2w, ln2b,
                                                   nullptr, fcW, fcb, (float*)d_out, N);
}